// Round 1
// 73.684 us; speedup vs baseline: 1.0107x; 1.0107x over previous
//
#include <hip/hip_runtime.h>

// NURBS surface evaluation, MI355X — single fused kernel (polish pass 2).
// Inputs:  cp (256,256,3) f32, kvx (1,260) f32, kvy (1,260) f32
// Output:  (1,1024,1024,3) f32
//
// Every block independently:
//  1. normalizes both knot vectors (clamp<0 -> 1e-4, blocked shfl-scan cumsum,
//     affine normalize) into LDS. Parallel-scan reassociation perturbs knots
//     ~1e-7 rel; output perturbation ~1e-6, far under the 6.3e-2 threshold.
//  2. computes Cox-de-Boor basis + wrapped control indices for its one e
//     (block-uniform) and its 256 f values (one per thread), in registers.
//     Polish: branchless 9-step binary search (no scc branches), fast
//     v_rcp_f32 for the 6 divides per eval (~1 ulp; error budget 6e-2),
//     predicated +-260 wrap instead of non-pow2 integer modulo.
//  3. 4x4 weighted blend of control points (768KB table, L2-resident;
//     e fixed per block, f-adjacent lanes hit the same cache lines).
//  4. repacks through LDS, stores coalesced float4.
// One dispatch total — the bench floor is harness reset fills (256MiB
// workspace poison at 80% HBM peak, ~42us, outside kernel_launch).

#define KLEN  260
#define NCTRL 256
#define OUTN  1024
#define DEG   3
#define EPSV  1e-5
#define CHUNK 5   // 52 lanes x 5 = 260 knots per wave

__device__ __forceinline__ void basis_eval(const float* __restrict__ k,
                                           int idx, float* w, int* ci) {
  const double step = (1.0 - 2.0 * (double)EPSV) / (double)(OUTN - 1);
  const float u = (float)((double)EPSV + (double)idx * step);

  // searchsorted(k, u, side='right') - 1, branchless.
  // Invariant: forall i<lo: k[i]<=u ; forall i>=hi: k[i]>u.
  // len 260 -> 0 in <=9 floor-halvings; once lo==hi, mid==lo==hi<260 and
  // k[mid]>u by the invariant, so extra iterations are exact no-ops.
  int lo = 0, hi = KLEN;
  #pragma unroll
  for (int it = 0; it < 9; ++it) {
    int mid = (lo + hi) >> 1;
    bool c = (k[mid] <= u);
    lo = c ? mid + 1 : lo;
    hi = c ? hi  : mid;
  }
  int span = lo - 1;
  if (u == k[NCTRL]) span = NCTRL - 1;

  // span in [0, 258]: li = span+1-j in [-2, 258]; ri = span+j in [1, 261].
  // One predicated correction replaces the magic-multiply % 260.
  float left[DEG + 1], right[DEG + 1], cols[DEG + 1];
  cols[0] = 1.f;
  #pragma unroll
  for (int j = 1; j <= DEG; ++j) {
    int li = span + 1 - j; if (li < 0)     li += KLEN;
    int ri = span + j;     if (ri >= KLEN) ri -= KLEN;
    left[j]  = u - k[li];
    right[j] = k[ri] - u;
    float saved = 0.f;
    #pragma unroll
    for (int r = 0; r < j; ++r) {
      // fast rcp: single v_rcp_f32 (~1 ulp) instead of the IEEE div sequence
      float temp = cols[r] * __builtin_amdgcn_rcpf(right[r + 1] + left[j - r]);
      cols[r] = saved + right[r + 1] * temp;
      saved = left[j - r] * temp;
    }
    cols[j] = saved;
  }
  #pragma unroll
  for (int l = 0; l <= DEG; ++l) {
    w[l]  = cols[l];
    ci[l] = (span - DEG + l) & (NCTRL - 1);
  }
}

__global__ __launch_bounds__(256) void nurbs_fused(
    const float* __restrict__ cp,
    const float* __restrict__ kvx, const float* __restrict__ kvy,
    float* __restrict__ out) {
  __shared__ float kn[2][KLEN];
  __shared__ float sbuf[256 * 3];

  const int t    = threadIdx.x;
  const int wave = t >> 6;
  const int lane = t & 63;

  // ---- knot normalization: wave 0 -> x knots, wave 1 -> y knots ----
  if (wave < 2) {
    const float* kv = (wave == 0) ? kvx : kvy;
    float v[CHUNK];
    float lsum = 0.f;
    if (lane < 52) {
      #pragma unroll
      for (int j = 0; j < CHUNK; ++j) {
        float x = kv[lane * CHUNK + j];
        x = (x < 0.f) ? 1e-4f : x;
        v[j] = x;
        lsum += x;
      }
    } else {
      #pragma unroll
      for (int j = 0; j < CHUNK; ++j) v[j] = 0.f;
    }
    // inclusive shfl scan of per-lane sums (wave64)
    float s = lsum;
    #pragma unroll
    for (int d = 1; d < 64; d <<= 1) {
      float n = __shfl_up(s, d);
      if (lane >= d) s += n;
    }
    const float excl  = s - lsum;
    const float total = __shfl(s, 51);     // cumsum[KLEN-1]
    const float c0    = __shfl(v[0], 0);   // cumsum[0]
    const float inv_d = 1.f / (total - c0);
    if (lane < 52) {
      float run = excl;
      #pragma unroll
      for (int j = 0; j < CHUNK; ++j) {
        run += v[j];
        kn[wave][lane * CHUNK + j] = (run - c0) * inv_d;
      }
    }
  }
  __syncthreads();

  const int bx    = blockIdx.x;
  const int e     = bx >> 2;
  const int fbase = (bx & 3) << 8;
  const int f     = fbase + t;

  float wE[4], wF[4];
  int   iE[4], iF[4];
  basis_eval(kn[0], e, wE, iE);   // block-uniform
  basis_eval(kn[1], f, wF, iF);   // per-thread

  float ax = 0.f, ay = 0.f, az = 0.f;
  #pragma unroll
  for (int l = 0; l < 4; ++l) {
    const float* rowp = cp + iE[l] * (NCTRL * 3);
    const float wl = wE[l];
    #pragma unroll
    for (int r = 0; r < 4; ++r) {
      const float w = wl * wF[r];
      const float* p = rowp + iF[r] * 3;
      ax = fmaf(w, p[0], ax);
      ay = fmaf(w, p[1], ay);
      az = fmaf(w, p[2], az);
    }
  }

  // repack through LDS -> coalesced float4 stores (stride-3 LDS is odd: no conflicts)
  sbuf[t * 3 + 0] = ax;
  sbuf[t * 3 + 1] = ay;
  sbuf[t * 3 + 2] = az;
  __syncthreads();

  float4* ob = (float4*)(out + (size_t)(e * OUTN + fbase) * 3);
  if (t < 192) ob[t] = ((const float4*)sbuf)[t];
}

extern "C" void kernel_launch(void* const* d_in, const int* in_sizes, int n_in,
                              void* d_out, int out_size, void* d_ws, size_t ws_size,
                              hipStream_t stream) {
  (void)in_sizes; (void)n_in; (void)out_size; (void)d_ws; (void)ws_size;
  const float* cp  = (const float*)d_in[0];
  const float* kvx = (const float*)d_in[1];
  const float* kvy = (const float*)d_in[2];
  float* out = (float*)d_out;

  nurbs_fused<<<4096, 256, 0, stream>>>(cp, kvx, kvy, out);
}

// Round 2
// 66.945 us; speedup vs baseline: 1.1124x; 1.1007x over previous
//
#include <hip/hip_runtime.h>

// NURBS surface evaluation, MI355X — single fused kernel (polish pass 3).
// Inputs:  cp (256,256,3) f32, kvx (1,260) f32, kvy (1,260) f32
// Output:  (1,1024,1024,3) f32
//
// Restructure vs pass 2: each block owns a 4x256 output tile (4 consecutive
// e-rows x 256 f-cols), 1024 blocks total.
//  - f-basis: computed ONCE per thread, reused for 4 outputs (was 4x).
//  - e-bases: computed once per BLOCK by 4 lanes, broadcast via LDS
//    (was per-thread).
//  - control-row sharing: spans are non-decreasing in e and advance ~0.25
//    per sample, so span(e3)-span(e0) <= 2 almost always. Shared path
//    builds 6 row-blends RB[i] = sum_r wF[r]*cp[span0-3+i, iF[r]] (24
//    gather loads) and combines with a zero-padded per-e weight table
//    wEp[e][i] (= wE[e][i-d_e] when in range) -> 4 outputs from 24 loads
//    instead of 64. Wide-span blocks (block-uniform branch, no lane
//    divergence) use the exact per-e fallback.
//  - repack 4 rows through 12KB LDS -> coalesced float4 stores.
// One dispatch total — the bench floor is harness reset fills (256MiB
// workspace poison at ~80% HBM peak, ~41us, outside kernel_launch).

#define KLEN  260
#define NCTRL 256
#define OUTN  1024
#define DEG   3
#define EPSV  1e-5
#define CHUNK 5   // 52 lanes x 5 = 260 knots per wave
#define WROWS 6   // shared-row window: covers span(e3)-span(e0) <= 2

__device__ __forceinline__ float uval(int idx) {
  const double step = (1.0 - 2.0 * (double)EPSV) / (double)(OUTN - 1);
  return (float)((double)EPSV + (double)idx * step);
}

__device__ __forceinline__ int find_span(const float* __restrict__ k, float u) {
  // searchsorted(k, u, side='right') - 1, branchless 9-step.
  int lo = 0, hi = KLEN;
  #pragma unroll
  for (int it = 0; it < 9; ++it) {
    int mid = (lo + hi) >> 1;
    bool c = (k[mid] <= u);
    lo = c ? mid + 1 : lo;
    hi = c ? hi : mid;
  }
  int span = lo - 1;
  if (u == k[NCTRL]) span = NCTRL - 1;
  return span;
}

__device__ __forceinline__ void basis_from_span(const float* __restrict__ k,
                                                float u, int span, float* w) {
  // span in [0,258]: li in [-2,258], ri in [1,261] -> one predicated wrap.
  float left[DEG + 1], right[DEG + 1], cols[DEG + 1];
  cols[0] = 1.f;
  #pragma unroll
  for (int j = 1; j <= DEG; ++j) {
    int li = span + 1 - j; if (li < 0)     li += KLEN;
    int ri = span + j;     if (ri >= KLEN) ri -= KLEN;
    left[j]  = u - k[li];
    right[j] = k[ri] - u;
    float saved = 0.f;
    #pragma unroll
    for (int r = 0; r < j; ++r) {
      float temp = cols[r] * __builtin_amdgcn_rcpf(right[r + 1] + left[j - r]);
      cols[r] = saved + right[r + 1] * temp;
      saved = left[j - r] * temp;
    }
    cols[j] = saved;
  }
  #pragma unroll
  for (int l = 0; l <= DEG; ++l) w[l] = cols[l];
}

__global__ __launch_bounds__(256) void nurbs_fused(
    const float* __restrict__ cp,
    const float* __restrict__ kvx, const float* __restrict__ kvy,
    float* __restrict__ out) {
  __shared__ float kn[2][KLEN];
  __shared__ float wEraw[4][4];
  __shared__ int   sspan[4];
  __shared__ float wEp[4][WROWS];
  __shared__ float sbuf[4][256 * 3];

  const int t    = threadIdx.x;
  const int wave = t >> 6;
  const int lane = t & 63;

  // ---- knot normalization: wave 0 -> x knots, wave 1 -> y knots ----
  if (wave < 2) {
    const float* kv = (wave == 0) ? kvx : kvy;
    float v[CHUNK];
    float lsum = 0.f;
    if (lane < 52) {
      #pragma unroll
      for (int j = 0; j < CHUNK; ++j) {
        float x = kv[lane * CHUNK + j];
        x = (x < 0.f) ? 1e-4f : x;
        v[j] = x;
        lsum += x;
      }
    } else {
      #pragma unroll
      for (int j = 0; j < CHUNK; ++j) v[j] = 0.f;
    }
    float s = lsum;
    #pragma unroll
    for (int d = 1; d < 64; d <<= 1) {
      float n = __shfl_up(s, d);
      if (lane >= d) s += n;
    }
    const float excl  = s - lsum;
    const float total = __shfl(s, 51);     // cumsum[KLEN-1]
    const float c0    = __shfl(v[0], 0);   // cumsum[0]
    const float inv_d = 1.f / (total - c0);
    if (lane < 52) {
      float run = excl;
      #pragma unroll
      for (int j = 0; j < CHUNK; ++j) {
        run += v[j];
        kn[wave][lane * CHUNK + j] = (run - c0) * inv_d;
      }
    }
  }
  __syncthreads();

  const int bx    = blockIdx.x;
  const int e0    = (bx >> 2) << 2;     // 256 e-groups of 4 rows
  const int fbase = (bx & 3) << 8;      // 4 f-groups of 256 cols
  const int f     = fbase + t;

  // ---- e-bases: 4 lanes compute, broadcast via LDS ----
  if (t < 4) {
    const float ue = uval(e0 + t);
    const int sp = find_span(kn[0], ue);
    sspan[t] = sp;
    float w4[4];
    basis_from_span(kn[0], ue, sp, w4);
    #pragma unroll
    for (int l = 0; l < 4; ++l) wEraw[t][l] = w4[l];
  }
  __syncthreads();

  // zero-padded shared-window weight table (lanes 0..23)
  if (t < 4 * WROWS) {
    const int e = t / WROWS, i = t % WROWS;
    const int d = sspan[e] - sspan[0];
    const int l = i - d;
    wEp[e][i] = ((unsigned)l < 4u) ? wEraw[e][l] : 0.f;
  }

  // ---- f-basis per thread (overlaps the tiny LDS setup above) ----
  const float uf = uval(f);
  const int spf = find_span(kn[1], uf);
  float wF[4];
  basis_from_span(kn[1], uf, spf, wF);
  int iF[4];
  #pragma unroll
  for (int r = 0; r < 4; ++r) iF[r] = (spf - DEG + r) & (NCTRL - 1);

  __syncthreads();

  const int span0 = sspan[0];
  const int sdiff = sspan[3] - span0;   // block-uniform

  float acc[4][3];
  #pragma unroll
  for (int e = 0; e < 4; ++e) {
    acc[e][0] = 0.f; acc[e][1] = 0.f; acc[e][2] = 0.f;
  }

  if (sdiff <= WROWS - 4) {
    // shared-row path: 6 row-blends feed all 4 e-rows (24 gather loads)
    #pragma unroll
    for (int i = 0; i < WROWS; ++i) {
      const int row = (span0 - DEG + i) & (NCTRL - 1);
      const float* rowp = cp + row * (NCTRL * 3);
      float rb0 = 0.f, rb1 = 0.f, rb2 = 0.f;
      #pragma unroll
      for (int r = 0; r < 4; ++r) {
        const float* p = rowp + iF[r] * 3;
        rb0 = fmaf(wF[r], p[0], rb0);
        rb1 = fmaf(wF[r], p[1], rb1);
        rb2 = fmaf(wF[r], p[2], rb2);
      }
      #pragma unroll
      for (int e = 0; e < 4; ++e) {
        const float we = wEp[e][i];   // LDS broadcast, imm offset
        acc[e][0] = fmaf(we, rb0, acc[e][0]);
        acc[e][1] = fmaf(we, rb1, acc[e][1]);
        acc[e][2] = fmaf(we, rb2, acc[e][2]);
      }
    }
  } else {
    // rare wide-span fallback: exact per-e 4x4 blend (block-uniform branch)
    #pragma unroll
    for (int e = 0; e < 4; ++e) {
      const int spe = sspan[e];
      #pragma unroll
      for (int l = 0; l < 4; ++l) {
        const int row = (spe - DEG + l) & (NCTRL - 1);
        const float* rowp = cp + row * (NCTRL * 3);
        const float wl = wEraw[e][l];
        #pragma unroll
        for (int r = 0; r < 4; ++r) {
          const float w = wl * wF[r];
          const float* p = rowp + iF[r] * 3;
          acc[e][0] = fmaf(w, p[0], acc[e][0]);
          acc[e][1] = fmaf(w, p[1], acc[e][1]);
          acc[e][2] = fmaf(w, p[2], acc[e][2]);
        }
      }
    }
  }

  // ---- repack through LDS -> coalesced float4 stores (stride-3: odd, no conflicts)
  #pragma unroll
  for (int e = 0; e < 4; ++e) {
    sbuf[e][t * 3 + 0] = acc[e][0];
    sbuf[e][t * 3 + 1] = acc[e][1];
    sbuf[e][t * 3 + 2] = acc[e][2];
  }
  __syncthreads();

  #pragma unroll
  for (int e = 0; e < 4; ++e) {
    if (t < 192) {
      float4* ob = (float4*)(out + (size_t)((e0 + e) * OUTN + fbase) * 3);
      ob[t] = ((const float4*)sbuf[e])[t];
    }
  }
}

extern "C" void kernel_launch(void* const* d_in, const int* in_sizes, int n_in,
                              void* d_out, int out_size, void* d_ws, size_t ws_size,
                              hipStream_t stream) {
  (void)in_sizes; (void)n_in; (void)out_size; (void)d_ws; (void)ws_size;
  const float* cp  = (const float*)d_in[0];
  const float* kvx = (const float*)d_in[1];
  const float* kvy = (const float*)d_in[2];
  float* out = (float*)d_out;

  nurbs_fused<<<1024, 256, 0, stream>>>(cp, kvx, kvy, out);
}